// Round 10
// baseline (92.338 us; speedup 1.0000x reference)
//
#include <hip/hip_runtime.h>

#define N_NODES 8192
#define M_EDGES 2048
#define KK      16
#define QKD     256
#define VD      256
#define P_PAIRS 120   // 16*15/2
#define CAP2    32    // max member edges per node (avg 4)
#define FSTRIDE (QKD + 4)
#define SCALE   0.17677669529663687f   // (256/8)^-0.5
#define FIXPT   4194304.0f             // 2^22 fixed-point scale for mean accum

typedef float floatx4 __attribute__((ext_vector_type(4)));  // plain vector type
// (__builtin_nontemporal_load rejects HIP_vector_type<float,4>)

// ---------------- K1: wave-per-row ballot scan of adj ----------------
// One wave64 per node row; nontemporal float4 loads (adj is stream-once).
// nedges built in ascending-m order (deterministic, no node-side atomics).
// Edge side: ticket-mod atomics -- NO zeroing needed: each edge gets exactly
// KK=16 increments per call, so (ticket & 15) is a permutation of 0..15
// regardless of ecounts' prior value. Block 0 also zeroes isum[256] for the
// fixed-point mean accumulator (kernel boundary = happens-before edge_weights).
__global__ __launch_bounds__(256) void scan_adj(const floatx4* __restrict__ adj4,
                                                unsigned int* __restrict__ ecounts,
                                                int* __restrict__ enodes,
                                                int* __restrict__ ncounts,
                                                int* __restrict__ nedges,
                                                int* __restrict__ isum) {
    if (blockIdx.x == 0) isum[threadIdx.x] = 0;   // VD == blockDim.x == 256
    int wid  = (blockIdx.x * blockDim.x + threadIdx.x) >> 6;   // node id
    int lane = threadIdx.x & 63;
    if (wid >= N_NODES) return;
    const floatx4* row = adj4 + wid * (M_EDGES / 4);
    unsigned long long below = (1ull << lane) - 1ull;
    int base = 0;
    #pragma unroll
    for (int c = 0; c < M_EDGES / 4 / 64; ++c) {        // 8 chunks, loads independent
        floatx4 a = __builtin_nontemporal_load(&row[c * 64 + lane]);
        unsigned long long b0 = __ballot(a.x > 0.f);
        unsigned long long b1 = __ballot(a.y > 0.f);
        unsigned long long b2 = __ballot(a.z > 0.f);
        unsigned long long b3 = __ballot(a.w > 0.f);
        if ((b0 | b1 | b2 | b3) != 0ull) {
            int pre = __popcll(b0 & below) + __popcll(b1 & below)
                    + __popcll(b2 & below) + __popcll(b3 & below);
            int mbase = (c * 64 + lane) * 4;
            float vals[4] = {a.x, a.y, a.z, a.w};
            int own = 0;
            #pragma unroll
            for (int j = 0; j < 4; ++j) {
                if (vals[j] > 0.f) {
                    int m = mbase + j;
                    int pos = base + pre + own;          // ascending-m position
                    if (pos < CAP2) nedges[wid * CAP2 + pos] = m;
                    unsigned int slot = atomicAdd(&ecounts[m], 1u) & (KK - 1);
                    enodes[m * KK + slot] = wid;
                    ++own;
                }
            }
        }
        base += __popcll(b0) + __popcll(b1) + __popcll(b2) + __popcll(b3);
    }
    if (lane == 0) ncounts[wid] = base;
}

// ---------------- K2: per-edge weight w[m] + fixed-point mean accumulation ----
// Integer atomicAdd is exact & commutative -> deterministic sum regardless of
// atomic order (a float atomicAdd would NOT be). isum[d] accumulates
// rint(w[m]*v[m][d]*2^22); attn divides by 2^22*M. Range: w<=0.5, |v|<~5,
// sum ~ N(0, 0.25*M) -> 6 sigma * 2^22 ~ 5.7e8 << 2^31. Quantization error
// after /M ~ 1e-9. Negligible vs 4.3e-2 threshold.
__global__ __launch_bounds__(256) void edge_weights(const float* __restrict__ x1,
                                                    const float* __restrict__ v,
                                                    const int* __restrict__ enodes,
                                                    float* __restrict__ w,
                                                    int* __restrict__ isum) {
    __shared__ float f[KK][FSTRIDE];   // 16.6 KB, float4-aligned rows
    __shared__ int   ids[KK];
    __shared__ float part[P_PAIRS][2];
    __shared__ float d2s[P_PAIRS];
    __shared__ float sigma2;
    __shared__ float esum[4];
    __shared__ float wm_sh;
    int m = blockIdx.x;
    int t = threadIdx.x;

    if (t < KK) ids[t] = enodes[m * KK + t];
    __syncthreads();
    if (t == 0) {      // sort -> deterministic order despite atomic scatter
        for (int a = 1; a < KK; ++a) {
            int x = ids[a]; int b = a - 1;
            while (b >= 0 && ids[b] > x) { ids[b + 1] = ids[b]; --b; }
            ids[b + 1] = x;
        }
    }
    __syncthreads();
    // float4 gather: 4 passes, 4 rows each; thread t -> row kb*4+(t>>6), col t&63
    #pragma unroll
    for (int kb = 0; kb < 4; ++kb) {
        int k = kb * 4 + (t >> 6);
        int c = t & 63;
        float4 val = ((const float4*)(x1 + ids[k] * QKD))[c];
        ((float4*)&f[k][0])[c] = val;
    }
    __syncthreads();

    if (t < 2 * P_PAIRS) {          // pair split across 2 threads (128 dims each)
        int p = t >> 1, hh = t & 1;
        int i = 0, pp = p;
        while (pp >= KK - 1 - i) { pp -= KK - 1 - i; ++i; }
        int j = i + 1 + pp;
        const float4* fi = (const float4*)&f[i][0];
        const float4* fj = (const float4*)&f[j][0];
        int base4 = hh << 5;
        float acc = 0.0f;
        #pragma unroll 4
        for (int dd = 0; dd < 32; ++dd) {
            float4 a = fi[base4 + dd], b = fj[base4 + dd];
            float dx = a.x - b.x, dy = a.y - b.y, dz = a.z - b.z, dw = a.w - b.w;
            acc += dx * dx + dy * dy + dz * dz + dw * dw;
        }
        part[p][hh] = acc;
    }
    __syncthreads();
    if (t < P_PAIRS) d2s[t] = part[t][0] + part[t][1];
    __syncthreads();

    if (t < P_PAIRS) {   // lower-median rank select (rank 59 of 120)
        float mine = d2s[t];
        int rank = 0;
        for (int q = 0; q < P_PAIRS; ++q) {
            float o = d2s[q];
            rank += (o < mine || (o == mine && q < t)) ? 1 : 0;
        }
        if (rank == (P_PAIRS - 1) / 2) sigma2 = mine * mine;
    }
    __syncthreads();

    float e = (t < P_PAIRS) ? expf(-d2s[t] / sigma2) : 0.0f;
    e += __shfl_xor(e, 32); e += __shfl_xor(e, 16); e += __shfl_xor(e, 8);
    e += __shfl_xor(e, 4);  e += __shfl_xor(e, 2);  e += __shfl_xor(e, 1);
    if ((t & 63) == 0) esum[t >> 6] = e;
    __syncthreads();
    if (t == 0) {
        float wm = (esum[0] + esum[1] + esum[2] + esum[3]) / (float)(KK * (KK - 1));
        w[m] = wm;
        wm_sh = wm;
    }
    __syncthreads();
    // fused mean accumulation: thread t owns dim t (coalesced 1KB row of v)
    int iv = (int)rintf(wm_sh * v[m * VD + t] * FIXPT);
    atomicAdd(&isum[t], iv);
}

// ---------------- K3: attention, wave-per-node, float4 per-lane dims ----------
// Lane l owns dims 4l..4l+3 (all inside head l>>3). Head score = 8-lane reduce
// (xor 1,2,4). Per member edge: 2 float4 loads + 3 shuffles + 1 online-softmax
// chain. Deterministic (ascending-m nedges; isum is exact int sum).
__global__ __launch_bounds__(256) void attn(
        const float* __restrict__ x1, const float* __restrict__ x2,
        const float* __restrict__ v,  const float* __restrict__ w,
        const int* __restrict__ ncounts, const int* __restrict__ nedges,
        const int* __restrict__ isum, float* __restrict__ out) {
    const int wid  = (blockIdx.x * blockDim.x + threadIdx.x) >> 6;  // node
    const int lane = threadIdx.x & 63;
    if (wid >= N_NODES) return;

    int C = ncounts[wid]; if (C > CAP2) C = CAP2;
    const int* ned = nedges + wid * CAP2;

    float4 q = ((const float4*)(x1 + wid * QKD))[lane];
    q.x *= SCALE; q.y *= SCALE; q.z *= SCALE; q.w *= SCALE;

    float mk = -INFINITY, lsum = 0.0f;
    float4 acc = {0.f, 0.f, 0.f, 0.f};
    for (int c = 0; c < C; ++c) {
        int m = ned[c];
        float wm = w[m];
        float4 k4 = ((const float4*)(x2 + m * QKD))[lane];
        float4 v4 = ((const float4*)(v  + m * VD))[lane];
        float p = q.x * k4.x + q.y * k4.y + q.z * k4.z + q.w * k4.w;
        p += __shfl_xor(p, 1);   // 8-lane group = one head (dims 32h..32h+31)
        p += __shfl_xor(p, 2);
        p += __shfl_xor(p, 4);
        float nm  = fmaxf(mk, p);
        float fac = expf(mk - nm);
        float e   = expf(p - nm);
        float ew  = e * wm;
        lsum = lsum * fac + e;
        acc.x = acc.x * fac + ew * v4.x;
        acc.y = acc.y * fac + ew * v4.y;
        acc.z = acc.z * fac + ew * v4.z;
        acc.w = acc.w * fac + ew * v4.w;
        mk = nm;
    }
    float4 o;
    if (C > 0) {
        float inv = 1.0f / lsum;
        o.x = acc.x * inv; o.y = acc.y * inv; o.z = acc.z * inv; o.w = acc.w * inv;
    } else {
        // empty row: softmax over all-NEG is uniform -> mean of w*v (exact int sum)
        int4 iv = ((const int4*)isum)[lane];
        const float inv = (1.0f / FIXPT) / (float)M_EDGES;
        o.x = (float)iv.x * inv; o.y = (float)iv.y * inv;
        o.z = (float)iv.z * inv; o.w = (float)iv.w * inv;
    }
    ((float4*)(out + wid * VD))[lane] = o;
}

extern "C" void kernel_launch(void* const* d_in, const int* in_sizes, int n_in,
                              void* d_out, int out_size, void* d_ws, size_t ws_size,
                              hipStream_t stream) {
    const float* x1  = (const float*)d_in[0];   // (N, 256)
    const float* x2  = (const float*)d_in[1];   // (M, 256)
    const float* v   = (const float*)d_in[2];   // (M, 256)
    const float* adj = (const float*)d_in[3];   // (N, M)
    float* out = (float*)d_out;                 // (N, 256)

    // workspace layout (all 4-byte elems), ~1.2 MB total; nothing host-zeroed
    float* w       = (float*)d_ws;                   // M
    int*   isum    = (int*)(w + M_EDGES);            // VD   (zeroed by scan blk 0)
    int*   ncounts = isum + VD;                      // N
    int*   enodes  = ncounts + N_NODES;              // M*KK
    int*   nedges  = enodes + M_EDGES * KK;          // N*CAP2
    unsigned int* ecounts = (unsigned int*)(nedges + N_NODES * CAP2); // M (ticket-mod)

    scan_adj<<<N_NODES / 4, 256, 0, stream>>>((const floatx4*)adj, ecounts,
                                              enodes, ncounts, nedges, isum);
    edge_weights<<<M_EDGES, 256, 0, stream>>>(x1, v, enodes, w, isum);
    attn<<<N_NODES / 4, 256, 0, stream>>>(x1, x2, v, w, ncounts, nedges, isum, out);
}

// Round 11
// 62.582 us; speedup vs baseline: 1.4755x; 1.4755x over previous
//
#include <hip/hip_runtime.h>

#define N_NODES 8192
#define M_EDGES 2048
#define KK      16
#define QKD     256
#define VD      256
#define P_PAIRS 120   // 16*15/2
#define CAP2    32    // max member edges per node (avg 4)
#define NPART   64    // mean-reduction partials
#define FSTRIDE (QKD + 4)
#define SCALE   0.17677669529663687f   // (256/8)^-0.5

typedef float floatx4 __attribute__((ext_vector_type(4)));  // plain vector type
// (__builtin_nontemporal_load rejects HIP_vector_type<float,4>)

// ---------------- K1: wave-per-row ballot scan of adj ----------------
// One wave64 per node row; nontemporal float4 loads (adj is stream-once).
// nedges built in ascending-m order (deterministic, no node-side atomics).
// Edge side: ticket-mod atomics -- NO zeroing needed: each edge gets exactly
// KK=16 increments per call, so atomicAdd tickets are consecutive and
// (ticket & 15) is a permutation of 0..15 regardless of ecounts' prior value
// (poison/accumulation safe). enodes order is atomic-order-dependent but
// edge_weights sorts ids -> deterministic downstream.
// NOTE (R10 lesson): do NOT fuse mean-accumulation atomics into any kernel —
// 524K RMWs onto 16 cache lines cost ~60us; the separate kernel costs ~4.5us.
__global__ __launch_bounds__(256) void scan_adj(const floatx4* __restrict__ adj4,
                                                unsigned int* __restrict__ ecounts,
                                                int* __restrict__ enodes,
                                                int* __restrict__ ncounts,
                                                int* __restrict__ nedges) {
    int wid  = (blockIdx.x * blockDim.x + threadIdx.x) >> 6;   // node id
    int lane = threadIdx.x & 63;
    if (wid >= N_NODES) return;
    const floatx4* row = adj4 + wid * (M_EDGES / 4);
    unsigned long long below = (1ull << lane) - 1ull;
    int base = 0;
    #pragma unroll
    for (int c = 0; c < M_EDGES / 4 / 64; ++c) {        // 8 chunks, loads independent
        floatx4 a = __builtin_nontemporal_load(&row[c * 64 + lane]);
        unsigned long long b0 = __ballot(a.x > 0.f);
        unsigned long long b1 = __ballot(a.y > 0.f);
        unsigned long long b2 = __ballot(a.z > 0.f);
        unsigned long long b3 = __ballot(a.w > 0.f);
        if ((b0 | b1 | b2 | b3) != 0ull) {
            int pre = __popcll(b0 & below) + __popcll(b1 & below)
                    + __popcll(b2 & below) + __popcll(b3 & below);
            int mbase = (c * 64 + lane) * 4;
            float vals[4] = {a.x, a.y, a.z, a.w};
            int own = 0;
            #pragma unroll
            for (int j = 0; j < 4; ++j) {
                if (vals[j] > 0.f) {
                    int m = mbase + j;
                    int pos = base + pre + own;          // ascending-m position
                    if (pos < CAP2) nedges[wid * CAP2 + pos] = m;
                    unsigned int slot = atomicAdd(&ecounts[m], 1u) & (KK - 1);
                    enodes[m * KK + slot] = wid;
                    ++own;
                }
            }
        }
        base += __popcll(b0) + __popcll(b1) + __popcll(b2) + __popcll(b3);
    }
    if (lane == 0) ncounts[wid] = base;
}

// ---------------- K2: per-edge weight w[m] ----------------
__global__ __launch_bounds__(256) void edge_weights(const float* __restrict__ x1,
                                                    const int* __restrict__ enodes,
                                                    float* __restrict__ w) {
    __shared__ float f[KK][FSTRIDE];   // 16.6 KB, float4-aligned rows
    __shared__ int   ids[KK];
    __shared__ float part[P_PAIRS][2];
    __shared__ float d2s[P_PAIRS];
    __shared__ float sigma2;
    __shared__ float esum[4];
    int m = blockIdx.x;
    int t = threadIdx.x;

    if (t < KK) ids[t] = enodes[m * KK + t];
    __syncthreads();
    if (t == 0) {      // sort -> deterministic order despite atomic scatter
        for (int a = 1; a < KK; ++a) {
            int x = ids[a]; int b = a - 1;
            while (b >= 0 && ids[b] > x) { ids[b + 1] = ids[b]; --b; }
            ids[b + 1] = x;
        }
    }
    __syncthreads();
    // float4 gather: 4 passes, 4 rows each; thread t -> row kb*4+(t>>6), col t&63
    #pragma unroll
    for (int kb = 0; kb < 4; ++kb) {
        int k = kb * 4 + (t >> 6);
        int c = t & 63;
        float4 val = ((const float4*)(x1 + ids[k] * QKD))[c];
        ((float4*)&f[k][0])[c] = val;
    }
    __syncthreads();

    if (t < 2 * P_PAIRS) {          // pair split across 2 threads (128 dims each)
        int p = t >> 1, hh = t & 1;
        int i = 0, pp = p;
        while (pp >= KK - 1 - i) { pp -= KK - 1 - i; ++i; }
        int j = i + 1 + pp;
        const float4* fi = (const float4*)&f[i][0];
        const float4* fj = (const float4*)&f[j][0];
        int base4 = hh << 5;
        float acc = 0.0f;
        #pragma unroll 4
        for (int dd = 0; dd < 32; ++dd) {
            float4 a = fi[base4 + dd], b = fj[base4 + dd];
            float dx = a.x - b.x, dy = a.y - b.y, dz = a.z - b.z, dw = a.w - b.w;
            acc += dx * dx + dy * dy + dz * dz + dw * dw;
        }
        part[p][hh] = acc;
    }
    __syncthreads();
    if (t < P_PAIRS) d2s[t] = part[t][0] + part[t][1];
    __syncthreads();

    if (t < P_PAIRS) {   // lower-median rank select (rank 59 of 120)
        float mine = d2s[t];
        int rank = 0;
        for (int q = 0; q < P_PAIRS; ++q) {
            float o = d2s[q];
            rank += (o < mine || (o == mine && q < t)) ? 1 : 0;
        }
        if (rank == (P_PAIRS - 1) / 2) sigma2 = mine * mine;
    }
    __syncthreads();

    float e = (t < P_PAIRS) ? expf(-d2s[t] / sigma2) : 0.0f;
    e += __shfl_xor(e, 32); e += __shfl_xor(e, 16); e += __shfl_xor(e, 8);
    e += __shfl_xor(e, 4);  e += __shfl_xor(e, 2);  e += __shfl_xor(e, 1);
    if ((t & 63) == 0) esum[t >> 6] = e;
    __syncthreads();
    if (t == 0) w[m] = (esum[0] + esum[1] + esum[2] + esum[3]) / (float)(KK * (KK - 1));
}

// ---------------- K3: deterministic partial sums of w[m]*v[m] ----------------
__global__ void mean_vv_part(const float* __restrict__ v, const float* __restrict__ w,
                             float* __restrict__ partials) {
    int t = threadIdx.x, b = blockIdx.x;   // NPART blocks x 32 edges each
    float acc = 0.0f;
    #pragma unroll 8
    for (int mm = 0; mm < M_EDGES / NPART; ++mm) {
        int m = b * (M_EDGES / NPART) + mm;
        acc += w[m] * v[m * VD + t];
    }
    partials[b * VD + t] = acc;
}

// ---------------- K4: attention, wave-per-node, float4 per-lane dims ----------
// Lane l owns dims 4l..4l+3 (all inside head l>>3). Head score = 8-lane reduce
// (xor 1,2,4). Per member edge: 2 float4 loads + 3 shuffles + 1 online-softmax
// chain. Deterministic (ascending-m nedges).
__global__ __launch_bounds__(256) void attn(
        const float* __restrict__ x1, const float* __restrict__ x2,
        const float* __restrict__ v,  const float* __restrict__ w,
        const int* __restrict__ ncounts, const int* __restrict__ nedges,
        const float* __restrict__ partials, float* __restrict__ out) {
    const int wid  = (blockIdx.x * blockDim.x + threadIdx.x) >> 6;  // node
    const int lane = threadIdx.x & 63;
    if (wid >= N_NODES) return;

    int C = ncounts[wid]; if (C > CAP2) C = CAP2;
    const int* ned = nedges + wid * CAP2;

    float4 q = ((const float4*)(x1 + wid * QKD))[lane];
    q.x *= SCALE; q.y *= SCALE; q.z *= SCALE; q.w *= SCALE;

    float mk = -INFINITY, lsum = 0.0f;
    float4 acc = {0.f, 0.f, 0.f, 0.f};
    for (int c = 0; c < C; ++c) {
        int m = ned[c];
        float wm = w[m];
        float4 k4 = ((const float4*)(x2 + m * QKD))[lane];
        float4 v4 = ((const float4*)(v  + m * VD))[lane];
        float p = q.x * k4.x + q.y * k4.y + q.z * k4.z + q.w * k4.w;
        p += __shfl_xor(p, 1);   // 8-lane group = one head (dims 32h..32h+31)
        p += __shfl_xor(p, 2);
        p += __shfl_xor(p, 4);
        float nm  = fmaxf(mk, p);
        float fac = expf(mk - nm);
        float e   = expf(p - nm);
        float ew  = e * wm;
        lsum = lsum * fac + e;
        acc.x = acc.x * fac + ew * v4.x;
        acc.y = acc.y * fac + ew * v4.y;
        acc.z = acc.z * fac + ew * v4.z;
        acc.w = acc.w * fac + ew * v4.w;
        mk = nm;
    }
    float4 o;
    if (C > 0) {
        float inv = 1.0f / lsum;
        o.x = acc.x * inv; o.y = acc.y * inv; o.z = acc.z * inv; o.w = acc.w * inv;
    } else {
        // empty row: softmax over all-NEG is uniform -> mean of w*v
        float4 s = {0.f, 0.f, 0.f, 0.f};
        #pragma unroll 8
        for (int b = 0; b < NPART; ++b) {
            float4 pp = ((const float4*)(partials + b * VD))[lane];
            s.x += pp.x; s.y += pp.y; s.z += pp.z; s.w += pp.w;
        }
        const float inv = 1.0f / (float)M_EDGES;
        o.x = s.x * inv; o.y = s.y * inv; o.z = s.z * inv; o.w = s.w * inv;
    }
    ((float4*)(out + wid * VD))[lane] = o;
}

extern "C" void kernel_launch(void* const* d_in, const int* in_sizes, int n_in,
                              void* d_out, int out_size, void* d_ws, size_t ws_size,
                              hipStream_t stream) {
    const float* x1  = (const float*)d_in[0];   // (N, 256)
    const float* x2  = (const float*)d_in[1];   // (M, 256)
    const float* v   = (const float*)d_in[2];   // (M, 256)
    const float* adj = (const float*)d_in[3];   // (N, M)
    float* out = (float*)d_out;                 // (N, 256)

    // workspace layout (all 4-byte elems), ~1.3 MB total; nothing needs zeroing
    float* w        = (float*)d_ws;                  // M
    float* partials = w + M_EDGES;                   // NPART*VD
    int*   ncounts  = (int*)(partials + NPART * VD); // N
    int*   enodes   = ncounts + N_NODES;             // M*KK
    int*   nedges   = enodes + M_EDGES * KK;         // N*CAP2
    unsigned int* ecounts = (unsigned int*)(nedges + N_NODES * CAP2); // M (ticket-mod, no init)

    scan_adj<<<N_NODES / 4, 256, 0, stream>>>((const floatx4*)adj, ecounts,
                                              enodes, ncounts, nedges);
    edge_weights<<<M_EDGES, 256, 0, stream>>>(x1, enodes, w);
    mean_vv_part<<<NPART, 256, 0, stream>>>(v, w, partials);
    attn<<<N_NODES / 4, 256, 0, stream>>>(x1, x2, v, w, ncounts, nedges, partials, out);
}